// Round 15
// baseline (217.359 us; speedup 1.0000x reference)
//
#include <hip/hip_runtime.h>

typedef short short8 __attribute__((ext_vector_type(8)));
typedef float f32x4 __attribute__((ext_vector_type(4)));

#define CST 3072  // cat row stride (6*512 channels)

__device__ __forceinline__ float bf2f(short s) {
  unsigned u = ((unsigned)(unsigned short)s) << 16;
  return __builtin_bit_cast(float, u);
}
__device__ __forceinline__ short f2bf(float f) {
  unsigned u = __builtin_bit_cast(unsigned, f);
  u = (u + 0x7FFFu + ((u >> 16) & 1u)) >> 16;
  return (short)u;
}
__device__ __forceinline__ void gl16(const short* g, short* l) {
  __builtin_amdgcn_global_load_lds(
      (const __attribute__((address_space(1))) unsigned*)g,
      (__attribute__((address_space(3))) unsigned*)l, 16, 0, 0);
}

// ---- merged init: blocks <1024 do NCHW->NHWC bf16 transpose of x;
// blocks >=1024 do scale_w->bf16, wdr reorder, stats zero.
__global__ __launch_bounds__(256) void k_init(const float* __restrict__ x,
                                              const float* __restrict__ sw,
                                              const float* __restrict__ w1, const float* __restrict__ w2,
                                              const float* __restrict__ w3, const float* __restrict__ w4,
                                              const float* __restrict__ w5,
                                              short* __restrict__ cat,
                                              short* __restrict__ wbf, short* __restrict__ wdr,
                                              float* __restrict__ stats) {
  __shared__ float tile[64][65];
  int b = blockIdx.x;
  int t = threadIdx.x;
  if (b < 1024) {
    int cblk = b & 7, h = (b >> 3) & 63, n = b >> 9;
    int c0 = cblk * 64;
    int lw = t & 63, grp = t >> 6;
    const float* xp = x + (((size_t)n * 512 + c0) * 64 + h) * 64;
#pragma unroll
    for (int i = 0; i < 16; ++i) {
      int cl = grp * 16 + i;
      tile[cl][lw] = xp[(size_t)cl * 4096 + lw];
    }
    __syncthreads();
    int cl = t & 63;
    size_t mbase = ((size_t)n * 64 + h) * 64;
#pragma unroll
    for (int i = 0; i < 16; ++i) {
      int w = grp * 16 + i;
      cat[(mbase + w) * CST + c0 + cl] = f2bf(tile[cl][w]);
    }
  } else {
    int idx = (b - 1024) * 256 + t;
    const int NS = 512 * 3072;
    const int NW = 5 * 9 * 32 * 512;
    if (idx < NS) {
      wbf[idx] = f2bf(sw[idx]);
    } else if (idx < NS + NW) {
      int j = idx - NS;
      int c = j & 511;
      int t2 = j >> 9;
      int oc = t2 & 31;
      int t3 = t2 >> 5;
      int tap = t3 % 9;
      int di = t3 / 9;
      float v = 0.f;
      if (oc < 27) {
        const float* wp = (di == 0) ? w1 : (di == 1) ? w2 : (di == 2) ? w3 : (di == 3) ? w4 : w5;
        v = wp[((oc * 512 + c) * 3 + tap / 3) * 3 + tap % 3];
      }
      wdr[j] = f2bf(v);
    } else if (idx < NS + NW + 1024) {
      stats[idx - NS - NW] = 0.f;
    }
  }
}

// ---- offset conv + softmax + corner-table build.
// Block = 128 thr (2 waves) = one image row (n,h): 64 positions.
// Wave covers 32 positions (2 m-tiles sharing B-frags): 2 b128/pos/tap.
// K split in halves (kh): LDS = A 32 KB + B 16 KB = 48 KB -> 3 blocks/CU
// (fo buffer aliases As: written only after all MFMA reads, extra barrier).
// Swizzle: LDS slot (row,ch) holds source chunk ch^(row&7).
// C/D layout: row (m=position) = quad*4+reg, col (n=oc) = l15.
__global__ __launch_bounds__(128) void k_conv(const short* __restrict__ xsrc,
                                              const short* __restrict__ wdr_all,
                                              int* __restrict__ ctab) {
  __shared__ short As[64 * 256];   // 32 KB: 64 cols x 256 ch (kh half)
  __shared__ short Bs[32 * 256];   // 16 KB: 32 oc x 256 ch
  float (*fo)[32][33] = (float (*)[32][33])(void*)As;  // aliased: used post-MFMA
  int tid = threadIdx.x;
  int wave = tid >> 6, lane = tid & 63;
  int l15 = lane & 15, quad = lane >> 4;
  int b = blockIdx.x;
  int di = b >> 7;
  int loc = b & 127;
  const int DIL[5] = {1, 6, 12, 24, 36};
  int d = DIL[di];
  int rid = (loc & 7) * 16 + (loc >> 3);  // xcd-affine row id (0..127)
  int h = rid & 63, n = rid >> 6;         // block-uniform row
  f32x4 acc[2][2];
  f32x4 zz = {0.f, 0.f, 0.f, 0.f};
#pragma unroll
  for (int i = 0; i < 2; ++i)
#pragma unroll
    for (int j = 0; j < 2; ++j) acc[i][j] = zz;
  const short8 z8 = {0, 0, 0, 0, 0, 0, 0, 0};
  // per-lane staging source offsets (slot q = i*128 + tid)
  int aoff[16];
  int boff[8];
#pragma unroll
  for (int i = 0; i < 16; ++i) {
    int q = i * 128 + tid;
    int w = q >> 5, ch = q & 31;
    aoff[i] = w * CST + (ch ^ (w & 7)) * 8;
  }
#pragma unroll
  for (int i = 0; i < 8; ++i) {
    int q = i * 128 + tid;
    int oc = q >> 5, ch = q & 31;
    boff[i] = oc * 512 + (ch ^ (oc & 7)) * 8;
  }
  const short* wbase = wdr_all + (size_t)di * 9 * 32 * 512;
  int rowb = (n << 12);
#pragma unroll 1
  for (int kh = 0; kh < 2; ++kh) {
    int lastty = -1;
#pragma unroll
    for (int tap = 0; tap < 9; ++tap) {
      int ty = tap / 3, tx = tap % 3;
      int hh = h + (ty - 1) * d;
      if ((unsigned)hh >= 64u) continue;   // block-uniform skip
      __syncthreads();                     // prior LDS reads complete
      if (ty != lastty) {                  // stage full row hh (A), kh half
        const short* abase = xsrc + (size_t)(rowb + (hh << 6)) * CST + kh * 256;
#pragma unroll
        for (int i = 0; i < 16; ++i)
          gl16(abase + aoff[i], As + (i * 128 + wave * 64) * 8);
        lastty = ty;
      }
      {                                    // stage B tap, kh half
        const short* bbase = wbase + tap * 32 * 512 + kh * 256;
#pragma unroll
        for (int i = 0; i < 8; ++i)
          gl16(bbase + boff[i], Bs + (i * 128 + wave * 64) * 8);
      }
      __syncthreads();                     // gl16 drained
      int s0 = wave * 32 + (tx - 1) * d;   // col of (mt,l15): s0 + mt*16 + l15
#pragma unroll
      for (int ks = 0; ks < 8; ++ks) {
        int c = ks * 4 + quad;
        short8 a[2], bb[2];
#pragma unroll
        for (int mt = 0; mt < 2; ++mt) {
          int wp = s0 + mt * 16 + l15;
          bool ok = (unsigned)wp < 64u;
          int wc = ok ? wp : 0;
          short8 av = *(const short8*)(As + wc * 256 + (c ^ (wc & 7)) * 8);
          a[mt] = ok ? av : z8;
        }
#pragma unroll
        for (int ot = 0; ot < 2; ++ot) {
          int oc = ot * 16 + l15;
          bb[ot] = *(const short8*)(Bs + oc * 256 + (c ^ (oc & 7)) * 8);
        }
#pragma unroll
        for (int mt = 0; mt < 2; ++mt)
#pragma unroll
          for (int ot = 0; ot < 2; ++ot)
            acc[mt][ot] = __builtin_amdgcn_mfma_f32_16x16x32_bf16(a[mt], bb[ot], acc[mt][ot], 0, 0, 0);
      }
    }
  }
  __syncthreads();   // all waves done reading As before fo (aliased) is written
  // write fo: C row (quad*4+r) = position, C col (l15) = oc
#pragma unroll
  for (int mt = 0; mt < 2; ++mt)
#pragma unroll
    for (int ot = 0; ot < 2; ++ot)
#pragma unroll
      for (int r = 0; r < 4; ++r)
        fo[wave][mt * 16 + quad * 4 + r][ot * 16 + l15] = acc[mt][ot][r];
  __syncthreads();
  if (tid < 64) {   // softmax: one position per thread (wave0)
    int p = tid;
    float* fp = fo[p >> 5][p & 31];
    float mx = fp[0];
#pragma unroll
    for (int k = 1; k < 9; ++k) mx = fmaxf(mx, fp[k]);
    float s = 0.f, e[9];
#pragma unroll
    for (int k = 0; k < 9; ++k) { e[k] = __expf(fp[k] - mx); s += e[k]; }
    float inv = 1.f / s;
#pragma unroll
    for (int k = 0; k < 9; ++k) fp[k] = e[k] * inv;
  }
  __syncthreads();
  // corner table: 64 pos x 9 taps = 576 tasks over 128 threads, 5 rounds
#pragma unroll
  for (int rr = 0; rr < 5; ++rr) {
    int task = rr * 128 + tid;
    if (task < 576) {
      int p = task / 9;
      int k = task - p * 9;
      const float* fp = fo[p >> 5][p & 31];
      float f = fp[k];
      float dy = fp[9 + 2 * k];
      float dx = fp[10 + 2 * k];
      float ys = (float)(h + (k / 3 - 1) * d) + dy;
      float xs = (float)(p + (k % 3 - 1) * d) + dx;
      float y0f = floorf(ys), x0f = floorf(xs);
      float wy1 = ys - y0f, wx1 = xs - x0f;
      float wy0 = 1.f - wy1, wx0 = 1.f - wx1;
      int y0 = (int)y0f, x0 = (int)x0f;
      int4 ent;
      int* ep = (int*)&ent;
#pragma unroll
      for (int cy = 0; cy < 2; ++cy)
#pragma unroll
        for (int cx = 0; cx < 2; ++cx) {
          int yy = y0 + cy, xx = x0 + cx;
          bool v = ((unsigned)yy < 64u) && ((unsigned)xx < 64u);
          float wt = f * (cy ? wy1 : wy0) * (cx ? wx1 : wx0);
          int row = v ? (yy * 64 + xx) : 0;
          unsigned wb = v ? (unsigned)(unsigned short)f2bf(wt) : 0u;
          ep[cy * 2 + cx] = row | (int)(wb << 16);
        }
      int mm = rowb + (h << 6) + p;
      ((int4*)ctab)[((size_t)di * 8192 + mm) * 9 + k] = ent;
    }
  }
}

// ---- deform bilinear sample from precomputed corner table (R10/R12 form:
// one position per wave — measured local optimum; L2-BW-bound ~80% ceiling).
__global__ __launch_bounds__(256, 4) void k_samp(const short* __restrict__ xsrc,
                                                 short* __restrict__ cat,
                                                 const int* __restrict__ ctab) {
  int tid = threadIdx.x;
  int wv = __builtin_amdgcn_readfirstlane(tid >> 6);
  int lane = tid & 63;
  int b = blockIdx.x;
  int di = b >> 11;
  int loc = b & 2047;
  int m = (loc & 7) * 1024 + (loc >> 3) * 4 + wv;  // xcd*1024 + slab*4 + wave
  int n = m >> 12;
  const int4* tp = (const int4*)ctab + ((size_t)di * 8192 + m) * 9;
  const short* xb = xsrc + (size_t)(n << 12) * CST + lane * 8;
  float acc[8] = {0.f, 0.f, 0.f, 0.f, 0.f, 0.f, 0.f, 0.f};
#pragma unroll
  for (int k = 0; k < 9; ++k) {
    int4 e = tp[k];
    const int* ep = (const int*)&e;
#pragma unroll
    for (int c = 0; c < 4; ++c) {
      int dw = ep[c];
      float wt = __builtin_bit_cast(float, (unsigned)dw & 0xFFFF0000u);
      int row = dw & 0xFFFF;
      const short8 vv = *(const short8*)(xb + (size_t)row * CST);
#pragma unroll
      for (int j = 0; j < 8; ++j) acc[j] += wt * bf2f(vv[j]);
    }
  }
  short8 o8;
#pragma unroll
  for (int j = 0; j < 8; ++j) o8[j] = f2bf(acc[j]);
  *(short8*)(cat + (size_t)m * CST + 512 * (di + 1) + lane * 8) = o8;
}

// ---- 1x1 fuse conv: 128x128 tile, half-K per block (kh), BK=32 (m97 shape):
// LDS 8+8 KB -> 4+ blocks/CU so the per-step vmcnt/barrier drains overlap
// across blocks. XOR-4 swizzle on k-chunks (conflict-free b128: 8 lanes per
// 4-bank group = the 1KB/128B minimum). global_load_lds width 16.
// XCD-affine: 8 blocks sharing an A m-tile land on one XCD.
// Y halves bf16, summed in stats/norm.
__global__ __launch_bounds__(256) void k_gemm(const short* __restrict__ A,
                                              const short* __restrict__ B,
                                              short* __restrict__ Y) {
  __shared__ short As[128 * 32];   // 8 KB: slot (row, c4) holds src chunk c4^(row&3)
  __shared__ short Bs[128 * 32];   // 8 KB
  int tid = threadIdx.x;
  int wave = tid >> 6, lane = tid & 63;
  int l15 = lane & 15, quad = lane >> 4;
  int bid = blockIdx.x;            // 0..511
  int xcd = bid & 7, s = bid >> 3;
  int mt = xcd * 8 + (s >> 3);     // same-XCD blocks share A m-tiles
  int nz = s & 7;
  int nt = nz & 3, kh = nz >> 2;
  int m0 = mt * 128, n0 = nt * 128;
  int kbeg = kh * 1536;
  int wm = (wave >> 1) * 64, wn = (wave & 1) * 64;
  f32x4 acc[4][4];
  f32x4 zz = {0.f, 0.f, 0.f, 0.f};
#pragma unroll
  for (int i = 0; i < 4; ++i)
#pragma unroll
    for (int j = 0; j < 4; ++j) acc[i][j] = zz;
  // staging: chunk q = it*256 + tid -> LDS slot q (lane-contiguous, 16B),
  // source row = q>>2, col-chunk c4 = (q&3) ^ (row&3)  [swizzle on source]
  const short* agp[2];
  const short* bgp[2];
  short* adst[2];
  short* bdst[2];
#pragma unroll
  for (int it = 0; it < 2; ++it) {
    int q = it * 256 + tid;
    int row = q >> 2;
    int c4 = (q & 3) ^ (row & 3);
    agp[it] = A + (size_t)(m0 + row) * CST + kbeg + c4 * 8;
    bgp[it] = B + (size_t)(n0 + row) * CST + kbeg + c4 * 8;
    adst[it] = As + q * 8;
    bdst[it] = Bs + q * 8;
  }
  int slotA = (wm + l15) & 3;   // row&3 for this lane's A rows (i*16 keeps it)
  int slotB = (wn + l15) & 3;
#pragma unroll 1
  for (int ks = 0; ks < 48; ++ks) {
    int ko = ks * 32;
    __syncthreads();
#pragma unroll
    for (int it = 0; it < 2; ++it) gl16(agp[it] + ko, adst[it]);
#pragma unroll
    for (int it = 0; it < 2; ++it) gl16(bgp[it] + ko, bdst[it]);
    __syncthreads();
    int ca = (quad ^ slotA) * 8;
    int cb = (quad ^ slotB) * 8;
    short8 af[4], bf[4];
#pragma unroll
    for (int i = 0; i < 4; ++i)
      af[i] = *(const short8*)(As + (wm + i * 16 + l15) * 32 + ca);
#pragma unroll
    for (int j = 0; j < 4; ++j)
      bf[j] = *(const short8*)(Bs + (wn + j * 16 + l15) * 32 + cb);
#pragma unroll
    for (int i = 0; i < 4; ++i)
#pragma unroll
      for (int j = 0; j < 4; ++j)
        acc[i][j] = __builtin_amdgcn_mfma_f32_16x16x32_bf16(af[i], bf[j], acc[i][j], 0, 0, 0);
  }
  short* Yp = Y + (size_t)kh * (8192 * 512);
#pragma unroll
  for (int i = 0; i < 4; ++i) {
    int row = m0 + wm + i * 16 + quad * 4;
#pragma unroll
    for (int j = 0; j < 4; ++j) {
      int col = n0 + wn + j * 16 + l15;
#pragma unroll
      for (int r = 0; r < 4; ++r)
        Yp[(size_t)(row + r) * 512 + col] = f2bf(acc[i][j][r]);
    }
  }
}

// ---- per-channel sum / sumsq over m of (y0+y1)
__global__ __launch_bounds__(256) void k_stats(const short* __restrict__ Y,
                                               float* __restrict__ stats) {
  const short* Y1 = Y + (size_t)8192 * 512;
  int tid = threadIdx.x;
  int mb = blockIdx.x * 32;
  float s0 = 0.f, q0 = 0.f, s1 = 0.f, q1 = 0.f;
  for (int r = 0; r < 32; ++r) {
    size_t ro = (size_t)(mb + r) * 512;
    float v0 = bf2f(Y[ro + tid]) + bf2f(Y1[ro + tid]);
    float v1 = bf2f(Y[ro + tid + 256]) + bf2f(Y1[ro + tid + 256]);
    s0 += v0; q0 += v0 * v0;
    s1 += v1; q1 += v1 * v1;
  }
  atomicAdd(&stats[tid], s0);
  atomicAdd(&stats[tid + 256], s1);
  atomicAdd(&stats[512 + tid], q0);
  atomicAdd(&stats[512 + tid + 256], q1);
}

// ---- normalize (y0+y1) + NHWC->NCHW transpose -> d_out
__global__ __launch_bounds__(256) void k_norm(const short* __restrict__ Y,
                                              const float* __restrict__ stats,
                                              const float* __restrict__ gamma,
                                              const float* __restrict__ beta,
                                              float* __restrict__ out) {
  __shared__ float tile[64][65];
  const short* Y1 = Y + (size_t)8192 * 512;
  int b = blockIdx.x;
  int cblk = b & 7, h = (b >> 3) & 63, n = b >> 9;
  int c0 = cblk * 64;
  int t = threadIdx.x;
  int cl = t & 63, grp = t >> 6;
  int c = c0 + cl;
  float mean = stats[c] * (1.f / 8192.f);
  float var = stats[512 + c] * (1.f / 8192.f) - mean * mean;
  float Ai = gamma[c] * rsqrtf(var + 1e-5f);
  float Bi = beta[c] - mean * Ai;
  size_t mbase = ((size_t)n * 64 + h) * 64;
#pragma unroll
  for (int i = 0; i < 16; ++i) {
    int w = grp * 16 + i;
    size_t ro = (mbase + w) * 512 + c;
    tile[w][cl] = (bf2f(Y[ro]) + bf2f(Y1[ro])) * Ai + Bi;
  }
  __syncthreads();
  float* op = out + (((size_t)n * 512 + c0) * 64 + h) * 64;
#pragma unroll
  for (int i = 0; i < 16; ++i) {
    int c2 = grp * 16 + i;
    op[(size_t)c2 * 4096 + cl] = tile[cl][c2];
  }
}

extern "C" void kernel_launch(void* const* d_in, const int* in_sizes, int n_in,
                              void* d_out, int out_size, void* d_ws, size_t ws_size,
                              hipStream_t stream) {
  const float* x  = (const float*)d_in[0];
  const float* w1 = (const float*)d_in[1];
  const float* w2 = (const float*)d_in[2];
  const float* w3 = (const float*)d_in[3];
  const float* w4 = (const float*)d_in[4];
  const float* w5 = (const float*)d_in[5];
  const float* sw = (const float*)d_in[6];
  const float* gamma = (const float*)d_in[7];
  const float* beta  = (const float*)d_in[8];
  float* out = (float*)d_out;

  char* ws = (char*)d_ws;
  // workspace layout (bytes):
  // cat   @ 0        : 8192*3072*2    = 50331648   (bf16, block0 = x NHWC)
  // wbf   @ 50331648 : 512*3072*2     = 3145728
  // wdr   @ 53477376 : 5*9*32*512*2   = 1474560
  // yb    @ 54951936 : 2*8192*512*2   = 16777216   (two bf16 K-halves)
  // stats @ 71729152 : 1024*4         = 4096
  // ctab  @ 71733248 : 40960*36*4     = 5898240    (corner table)
  short* cat   = (short*)ws;
  short* wbf   = (short*)(ws + 50331648);
  short* wdr   = (short*)(ws + 53477376);
  short* yb    = (short*)(ws + 54951936);
  float* stats = (float*)(ws + 71729152);
  int*   ctab  = (int*)(ws + 71733248);

  k_init<<<10052, 256, 0, stream>>>(x, sw, w1, w2, w3, w4, w5, cat, wbf, wdr, stats);
  k_conv<<<640, 128, 0, stream>>>(cat, wdr, ctab);
  k_samp<<<10240, 256, 0, stream>>>(cat, cat, ctab);
  k_gemm<<<512, 256, 0, stream>>>(cat, wbf, yb);
  k_stats<<<256, 256, 0, stream>>>(yb, stats);
  k_norm<<<1024, 256, 0, stream>>>(yb, stats, gamma, beta, out);
}

// Round 16
// 208.762 us; speedup vs baseline: 1.0412x; 1.0412x over previous
//
#include <hip/hip_runtime.h>

typedef short short8 __attribute__((ext_vector_type(8)));
typedef float f32x4 __attribute__((ext_vector_type(4)));

#define CST 3072  // cat row stride (6*512 channels)

__device__ __forceinline__ float bf2f(short s) {
  unsigned u = ((unsigned)(unsigned short)s) << 16;
  return __builtin_bit_cast(float, u);
}
__device__ __forceinline__ short f2bf(float f) {
  unsigned u = __builtin_bit_cast(unsigned, f);
  u = (u + 0x7FFFu + ((u >> 16) & 1u)) >> 16;
  return (short)u;
}
__device__ __forceinline__ void gl16(const short* g, short* l) {
  __builtin_amdgcn_global_load_lds(
      (const __attribute__((address_space(1))) unsigned*)g,
      (__attribute__((address_space(3))) unsigned*)l, 16, 0, 0);
}

// ---- merged init: blocks <1024 do NCHW->NHWC bf16 transpose of x;
// blocks >=1024 do scale_w->bf16, wdr reorder, stats zero.
__global__ __launch_bounds__(256) void k_init(const float* __restrict__ x,
                                              const float* __restrict__ sw,
                                              const float* __restrict__ w1, const float* __restrict__ w2,
                                              const float* __restrict__ w3, const float* __restrict__ w4,
                                              const float* __restrict__ w5,
                                              short* __restrict__ cat,
                                              short* __restrict__ wbf, short* __restrict__ wdr,
                                              float* __restrict__ stats) {
  __shared__ float tile[64][65];
  int b = blockIdx.x;
  int t = threadIdx.x;
  if (b < 1024) {
    int cblk = b & 7, h = (b >> 3) & 63, n = b >> 9;
    int c0 = cblk * 64;
    int lw = t & 63, grp = t >> 6;
    const float* xp = x + (((size_t)n * 512 + c0) * 64 + h) * 64;
#pragma unroll
    for (int i = 0; i < 16; ++i) {
      int cl = grp * 16 + i;
      tile[cl][lw] = xp[(size_t)cl * 4096 + lw];
    }
    __syncthreads();
    int cl = t & 63;
    size_t mbase = ((size_t)n * 64 + h) * 64;
#pragma unroll
    for (int i = 0; i < 16; ++i) {
      int w = grp * 16 + i;
      cat[(mbase + w) * CST + c0 + cl] = f2bf(tile[cl][w]);
    }
  } else {
    int idx = (b - 1024) * 256 + t;
    const int NS = 512 * 3072;
    const int NW = 5 * 9 * 32 * 512;
    if (idx < NS) {
      wbf[idx] = f2bf(sw[idx]);
    } else if (idx < NS + NW) {
      int j = idx - NS;
      int c = j & 511;
      int t2 = j >> 9;
      int oc = t2 & 31;
      int t3 = t2 >> 5;
      int tap = t3 % 9;
      int di = t3 / 9;
      float v = 0.f;
      if (oc < 27) {
        const float* wp = (di == 0) ? w1 : (di == 1) ? w2 : (di == 2) ? w3 : (di == 3) ? w4 : w5;
        v = wp[((oc * 512 + c) * 3 + tap / 3) * 3 + tap % 3];
      }
      wdr[j] = f2bf(v);
    } else if (idx < NS + NW + 1024) {
      stats[idx - NS - NW] = 0.f;
    }
  }
}

// ---- offset conv + softmax + corner-table build.
// Block = 128 thr (2 waves) = one image row (n,h): 64 positions.
// Wave covers 32 positions (2 m-tiles sharing B-frags): 2 b128/pos/tap.
// K split in halves (kh): LDS = A 32 KB + B 16 KB = 48 KB -> 3 blocks/CU
// (fo buffer aliases As: written only after all MFMA reads, extra barrier).
// Swizzle: LDS slot (row,ch) holds source chunk ch^(row&7).
// C/D layout: row (m=position) = quad*4+reg, col (n=oc) = l15.
__global__ __launch_bounds__(128) void k_conv(const short* __restrict__ xsrc,
                                              const short* __restrict__ wdr_all,
                                              int* __restrict__ ctab) {
  __shared__ short As[64 * 256];   // 32 KB: 64 cols x 256 ch (kh half)
  __shared__ short Bs[32 * 256];   // 16 KB: 32 oc x 256 ch
  float (*fo)[32][33] = (float (*)[32][33])(void*)As;  // aliased: used post-MFMA
  int tid = threadIdx.x;
  int wave = tid >> 6, lane = tid & 63;
  int l15 = lane & 15, quad = lane >> 4;
  int b = blockIdx.x;
  int di = b >> 7;
  int loc = b & 127;
  const int DIL[5] = {1, 6, 12, 24, 36};
  int d = DIL[di];
  int rid = (loc & 7) * 16 + (loc >> 3);  // xcd-affine row id (0..127)
  int h = rid & 63, n = rid >> 6;         // block-uniform row
  f32x4 acc[2][2];
  f32x4 zz = {0.f, 0.f, 0.f, 0.f};
#pragma unroll
  for (int i = 0; i < 2; ++i)
#pragma unroll
    for (int j = 0; j < 2; ++j) acc[i][j] = zz;
  const short8 z8 = {0, 0, 0, 0, 0, 0, 0, 0};
  // per-lane staging source offsets (slot q = i*128 + tid)
  int aoff[16];
  int boff[8];
#pragma unroll
  for (int i = 0; i < 16; ++i) {
    int q = i * 128 + tid;
    int w = q >> 5, ch = q & 31;
    aoff[i] = w * CST + (ch ^ (w & 7)) * 8;
  }
#pragma unroll
  for (int i = 0; i < 8; ++i) {
    int q = i * 128 + tid;
    int oc = q >> 5, ch = q & 31;
    boff[i] = oc * 512 + (ch ^ (oc & 7)) * 8;
  }
  const short* wbase = wdr_all + (size_t)di * 9 * 32 * 512;
  int rowb = (n << 12);
#pragma unroll 1
  for (int kh = 0; kh < 2; ++kh) {
    int lastty = -1;
#pragma unroll
    for (int tap = 0; tap < 9; ++tap) {
      int ty = tap / 3, tx = tap % 3;
      int hh = h + (ty - 1) * d;
      if ((unsigned)hh >= 64u) continue;   // block-uniform skip
      __syncthreads();                     // prior LDS reads complete
      if (ty != lastty) {                  // stage full row hh (A), kh half
        const short* abase = xsrc + (size_t)(rowb + (hh << 6)) * CST + kh * 256;
#pragma unroll
        for (int i = 0; i < 16; ++i)
          gl16(abase + aoff[i], As + (i * 128 + wave * 64) * 8);
        lastty = ty;
      }
      {                                    // stage B tap, kh half
        const short* bbase = wbase + tap * 32 * 512 + kh * 256;
#pragma unroll
        for (int i = 0; i < 8; ++i)
          gl16(bbase + boff[i], Bs + (i * 128 + wave * 64) * 8);
      }
      __syncthreads();                     // gl16 drained
      int s0 = wave * 32 + (tx - 1) * d;   // col of (mt,l15): s0 + mt*16 + l15
#pragma unroll
      for (int ks = 0; ks < 8; ++ks) {
        int c = ks * 4 + quad;
        short8 a[2], bb[2];
#pragma unroll
        for (int mt = 0; mt < 2; ++mt) {
          int wp = s0 + mt * 16 + l15;
          bool ok = (unsigned)wp < 64u;
          int wc = ok ? wp : 0;
          short8 av = *(const short8*)(As + wc * 256 + (c ^ (wc & 7)) * 8);
          a[mt] = ok ? av : z8;
        }
#pragma unroll
        for (int ot = 0; ot < 2; ++ot) {
          int oc = ot * 16 + l15;
          bb[ot] = *(const short8*)(Bs + oc * 256 + (c ^ (oc & 7)) * 8);
        }
#pragma unroll
        for (int mt = 0; mt < 2; ++mt)
#pragma unroll
          for (int ot = 0; ot < 2; ++ot)
            acc[mt][ot] = __builtin_amdgcn_mfma_f32_16x16x32_bf16(a[mt], bb[ot], acc[mt][ot], 0, 0, 0);
      }
    }
  }
  __syncthreads();   // all waves done reading As before fo (aliased) is written
  // write fo: C row (quad*4+r) = position, C col (l15) = oc
#pragma unroll
  for (int mt = 0; mt < 2; ++mt)
#pragma unroll
    for (int ot = 0; ot < 2; ++ot)
#pragma unroll
      for (int r = 0; r < 4; ++r)
        fo[wave][mt * 16 + quad * 4 + r][ot * 16 + l15] = acc[mt][ot][r];
  __syncthreads();
  if (tid < 64) {   // softmax: one position per thread (wave0)
    int p = tid;
    float* fp = fo[p >> 5][p & 31];
    float mx = fp[0];
#pragma unroll
    for (int k = 1; k < 9; ++k) mx = fmaxf(mx, fp[k]);
    float s = 0.f, e[9];
#pragma unroll
    for (int k = 0; k < 9; ++k) { e[k] = __expf(fp[k] - mx); s += e[k]; }
    float inv = 1.f / s;
#pragma unroll
    for (int k = 0; k < 9; ++k) fp[k] = e[k] * inv;
  }
  __syncthreads();
  // corner table: 64 pos x 9 taps = 576 tasks over 128 threads, 5 rounds
#pragma unroll
  for (int rr = 0; rr < 5; ++rr) {
    int task = rr * 128 + tid;
    if (task < 576) {
      int p = task / 9;
      int k = task - p * 9;
      const float* fp = fo[p >> 5][p & 31];
      float f = fp[k];
      float dy = fp[9 + 2 * k];
      float dx = fp[10 + 2 * k];
      float ys = (float)(h + (k / 3 - 1) * d) + dy;
      float xs = (float)(p + (k % 3 - 1) * d) + dx;
      float y0f = floorf(ys), x0f = floorf(xs);
      float wy1 = ys - y0f, wx1 = xs - x0f;
      float wy0 = 1.f - wy1, wx0 = 1.f - wx1;
      int y0 = (int)y0f, x0 = (int)x0f;
      int4 ent;
      int* ep = (int*)&ent;
#pragma unroll
      for (int cy = 0; cy < 2; ++cy)
#pragma unroll
        for (int cx = 0; cx < 2; ++cx) {
          int yy = y0 + cy, xx = x0 + cx;
          bool v = ((unsigned)yy < 64u) && ((unsigned)xx < 64u);
          float wt = f * (cy ? wy1 : wy0) * (cx ? wx1 : wx0);
          int row = v ? (yy * 64 + xx) : 0;
          unsigned wb = v ? (unsigned)(unsigned short)f2bf(wt) : 0u;
          ep[cy * 2 + cx] = row | (int)(wb << 16);
        }
      int mm = rowb + (h << 6) + p;
      ((int4*)ctab)[((size_t)di * 8192 + mm) * 9 + k] = ent;
    }
  }
}

// ---- deform bilinear sample from precomputed corner table (R10/R12 form:
// one position per wave — measured local optimum; L2-BW-bound ~80% ceiling).
__global__ __launch_bounds__(256, 4) void k_samp(const short* __restrict__ xsrc,
                                                 short* __restrict__ cat,
                                                 const int* __restrict__ ctab) {
  int tid = threadIdx.x;
  int wv = __builtin_amdgcn_readfirstlane(tid >> 6);
  int lane = tid & 63;
  int b = blockIdx.x;
  int di = b >> 11;
  int loc = b & 2047;
  int m = (loc & 7) * 1024 + (loc >> 3) * 4 + wv;  // xcd*1024 + slab*4 + wave
  int n = m >> 12;
  const int4* tp = (const int4*)ctab + ((size_t)di * 8192 + m) * 9;
  const short* xb = xsrc + (size_t)(n << 12) * CST + lane * 8;
  float acc[8] = {0.f, 0.f, 0.f, 0.f, 0.f, 0.f, 0.f, 0.f};
#pragma unroll
  for (int k = 0; k < 9; ++k) {
    int4 e = tp[k];
    const int* ep = (const int*)&e;
#pragma unroll
    for (int c = 0; c < 4; ++c) {
      int dw = ep[c];
      float wt = __builtin_bit_cast(float, (unsigned)dw & 0xFFFF0000u);
      int row = dw & 0xFFFF;
      const short8 vv = *(const short8*)(xb + (size_t)row * CST);
#pragma unroll
      for (int j = 0; j < 8; ++j) acc[j] += wt * bf2f(vv[j]);
    }
  }
  short8 o8;
#pragma unroll
  for (int j = 0; j < 8; ++j) o8[j] = f2bf(acc[j]);
  *(short8*)(cat + (size_t)m * CST + 512 * (di + 1) + lane * 8) = o8;
}

// ---- 1x1 fuse conv: 128x128 tile, half-K per block (kh), BK=64,
// XOR-swizzled LDS (conflict-free ds_read_b128), global_load_lds width 16.
// XCD-affine: 8 blocks sharing an A m-tile land on one XCD (A read once/XCD).
// Y halves bf16, summed in stats/norm. [R14 form — measured best]
__global__ __launch_bounds__(256) void k_gemm(const short* __restrict__ A,
                                              const short* __restrict__ B,
                                              short* __restrict__ Y) {
  __shared__ short As[128 * 64];   // 16 KB, swizzled: slot c8' = c8 ^ (row&7)
  __shared__ short Bs[128 * 64];   // 16 KB
  int tid = threadIdx.x;
  int wave = tid >> 6, lane = tid & 63;
  int l15 = lane & 15, quad = lane >> 4;
  int bid = blockIdx.x;            // 0..511
  int xcd = bid & 7, s = bid >> 3;
  int mt = xcd * 8 + (s >> 3);     // same-XCD blocks share A m-tiles
  int nz = s & 7;
  int nt = nz & 3, kh = nz >> 2;
  int m0 = mt * 128, n0 = nt * 128;
  int kbeg = kh * 1536;
  int wm = (wave >> 1) * 64, wn = (wave & 1) * 64;
  f32x4 acc[4][4];
  f32x4 zz = {0.f, 0.f, 0.f, 0.f};
#pragma unroll
  for (int i = 0; i < 4; ++i)
#pragma unroll
    for (int j = 0; j < 4; ++j) acc[i][j] = zz;
  // staging: chunk q = it*256 + tid -> LDS slot q (lane-contiguous),
  // source row = q>>3, col-chunk c8g = (q&7) ^ (row&7)  [swizzle on source]
  const short* agp[4];
  const short* bgp[4];
  short* adst[4];
  short* bdst[4];
#pragma unroll
  for (int it = 0; it < 4; ++it) {
    int q = it * 256 + tid;
    int row = q >> 3;
    int c8g = (q & 7) ^ (row & 7);
    agp[it] = A + (size_t)(m0 + row) * CST + kbeg + c8g * 8;
    bgp[it] = B + (size_t)(n0 + row) * CST + kbeg + c8g * 8;
    adst[it] = As + q * 8;
    bdst[it] = Bs + q * 8;
  }
  int slotbA = (wm + l15) & 7;
  int slotbB = (wn + l15) & 7;
#pragma unroll 1
  for (int ks = 0; ks < 24; ++ks) {
    int ko = ks * 64;
    __syncthreads();
#pragma unroll
    for (int it = 0; it < 4; ++it) gl16(agp[it] + ko, adst[it]);
#pragma unroll
    for (int it = 0; it < 4; ++it) gl16(bgp[it] + ko, bdst[it]);
    __syncthreads();
#pragma unroll
    for (int kk = 0; kk < 2; ++kk) {
      int sa = ((quad + kk * 4) ^ slotbA) * 8;
      int sb = ((quad + kk * 4) ^ slotbB) * 8;
      short8 af[4], bf[4];
#pragma unroll
      for (int i = 0; i < 4; ++i)
        af[i] = *(const short8*)(As + (wm + i * 16 + l15) * 64 + sa);
#pragma unroll
      for (int j = 0; j < 4; ++j)
        bf[j] = *(const short8*)(Bs + (wn + j * 16 + l15) * 64 + sb);
#pragma unroll
      for (int i = 0; i < 4; ++i)
#pragma unroll
        for (int j = 0; j < 4; ++j)
          acc[i][j] = __builtin_amdgcn_mfma_f32_16x16x32_bf16(af[i], bf[j], acc[i][j], 0, 0, 0);
    }
  }
  short* Yp = Y + (size_t)kh * (8192 * 512);
#pragma unroll
  for (int i = 0; i < 4; ++i) {
    int row = m0 + wm + i * 16 + quad * 4;
#pragma unroll
    for (int j = 0; j < 4; ++j) {
      int col = n0 + wn + j * 16 + l15;
#pragma unroll
      for (int r = 0; r < 4; ++r)
        Yp[(size_t)(row + r) * 512 + col] = f2bf(acc[i][j][r]);
    }
  }
}

// ---- per-channel sum / sumsq over m of (y0+y1)
__global__ __launch_bounds__(256) void k_stats(const short* __restrict__ Y,
                                               float* __restrict__ stats) {
  const short* Y1 = Y + (size_t)8192 * 512;
  int tid = threadIdx.x;
  int mb = blockIdx.x * 32;
  float s0 = 0.f, q0 = 0.f, s1 = 0.f, q1 = 0.f;
  for (int r = 0; r < 32; ++r) {
    size_t ro = (size_t)(mb + r) * 512;
    float v0 = bf2f(Y[ro + tid]) + bf2f(Y1[ro + tid]);
    float v1 = bf2f(Y[ro + tid + 256]) + bf2f(Y1[ro + tid + 256]);
    s0 += v0; q0 += v0 * v0;
    s1 += v1; q1 += v1 * v1;
  }
  atomicAdd(&stats[tid], s0);
  atomicAdd(&stats[tid + 256], s1);
  atomicAdd(&stats[512 + tid], q0);
  atomicAdd(&stats[512 + tid + 256], q1);
}

// ---- normalize (y0+y1) + NHWC->NCHW transpose -> d_out
__global__ __launch_bounds__(256) void k_norm(const short* __restrict__ Y,
                                              const float* __restrict__ stats,
                                              const float* __restrict__ gamma,
                                              const float* __restrict__ beta,
                                              float* __restrict__ out) {
  __shared__ float tile[64][65];
  const short* Y1 = Y + (size_t)8192 * 512;
  int b = blockIdx.x;
  int cblk = b & 7, h = (b >> 3) & 63, n = b >> 9;
  int c0 = cblk * 64;
  int t = threadIdx.x;
  int cl = t & 63, grp = t >> 6;
  int c = c0 + cl;
  float mean = stats[c] * (1.f / 8192.f);
  float var = stats[512 + c] * (1.f / 8192.f) - mean * mean;
  float Ai = gamma[c] * rsqrtf(var + 1e-5f);
  float Bi = beta[c] - mean * Ai;
  size_t mbase = ((size_t)n * 64 + h) * 64;
#pragma unroll
  for (int i = 0; i < 16; ++i) {
    int w = grp * 16 + i;
    size_t ro = (mbase + w) * 512 + c;
    tile[w][cl] = (bf2f(Y[ro]) + bf2f(Y1[ro])) * Ai + Bi;
  }
  __syncthreads();
  float* op = out + (((size_t)n * 512 + c0) * 64 + h) * 64;
#pragma unroll
  for (int i = 0; i < 16; ++i) {
    int c2 = grp * 16 + i;
    op[(size_t)c2 * 4096 + cl] = tile[cl][c2];
  }
}

extern "C" void kernel_launch(void* const* d_in, const int* in_sizes, int n_in,
                              void* d_out, int out_size, void* d_ws, size_t ws_size,
                              hipStream_t stream) {
  const float* x  = (const float*)d_in[0];
  const float* w1 = (const float*)d_in[1];
  const float* w2 = (const float*)d_in[2];
  const float* w3 = (const float*)d_in[3];
  const float* w4 = (const float*)d_in[4];
  const float* w5 = (const float*)d_in[5];
  const float* sw = (const float*)d_in[6];
  const float* gamma = (const float*)d_in[7];
  const float* beta  = (const float*)d_in[8];
  float* out = (float*)d_out;

  char* ws = (char*)d_ws;
  // workspace layout (bytes):
  // cat   @ 0        : 8192*3072*2    = 50331648   (bf16, block0 = x NHWC)
  // wbf   @ 50331648 : 512*3072*2     = 3145728
  // wdr   @ 53477376 : 5*9*32*512*2   = 1474560
  // yb    @ 54951936 : 2*8192*512*2   = 16777216   (two bf16 K-halves)
  // stats @ 71729152 : 1024*4         = 4096
  // ctab  @ 71733248 : 40960*36*4     = 5898240    (corner table)
  short* cat   = (short*)ws;
  short* wbf   = (short*)(ws + 50331648);
  short* wdr   = (short*)(ws + 53477376);
  short* yb    = (short*)(ws + 54951936);
  float* stats = (float*)(ws + 71729152);
  int*   ctab  = (int*)(ws + 71733248);

  k_init<<<10052, 256, 0, stream>>>(x, sw, w1, w2, w3, w4, w5, cat, wbf, wdr, stats);
  k_conv<<<640, 128, 0, stream>>>(cat, wdr, ctab);
  k_samp<<<10240, 256, 0, stream>>>(cat, cat, ctab);
  k_gemm<<<512, 256, 0, stream>>>(cat, wbf, yb);
  k_stats<<<256, 256, 0, stream>>>(yb, stats);
  k_norm<<<1024, 256, 0, stream>>>(yb, stats, gamma, beta, out);
}